// Round 4
// baseline (373.323 us; speedup 1.0000x reference)
//
#include <hip/hip_runtime.h>
#include <hip/hip_bf16.h>
#include <hip/hip_cooperative_groups.h>

namespace cg = cooperative_groups;

// ---------------------------------------------------------------------------
//   x_e  [2,128,24,24,24]   pred [2,32,96,96,96]   out [2,3,96,96,96] fp32
//   conv(128->256,k3,s2,VALID) -> 11^3 positions; mean∘conv commutes, so
//   conv+pool collapses to 27 window-sums per channel (exact).
// ---------------------------------------------------------------------------

#define NSPAT 13824      // 24^3
#define P4    221184     // 96^3/4

// ws layout (floats)
#define WS_STATSPART 0       // 512 float2 -> 1024
#define WS_WINS      1024    // [2][128][4][27] = 27648
#define WS_XF        28672   // 512
#define WS_P         29184   // 6*512 = 3072
#define WS_EFFW      32256   // 192
#define WS_SINK      32448

struct KArgs {
  const float *x_e, *pred, *gn_g, *gn_b, *gap_w, *gap_b, *w_cf, *b_cf;
  const float *w_c, *b_c, *w_a1, *b_a1, *w_a2, *b_a2, *emb, *w_seg, *b_seg;
  float *ws, *out;
};

// Phases: 0 stats+prefetch, 1 winsum, 2 xfeat, 3 ctrl1, 4 ctrl2+3, 5 seg.
// Every phase is task-stride over gridDim.x, so ANY grid size is correct.
// Coop launch runs (0..5) with grid.sync between phases; fallback launches
// one phase per kernel (launch boundary = global sync).
__global__ __launch_bounds__(256) void fused_kernel(KArgs a, int ph_lo, int ph_hi) {
  __shared__ float smem[4140];
  const int t  = threadIdx.x;
  const int nb = gridDim.x;

  for (int ph = ph_lo; ph <= ph_hi; ++ph) {
    if (ph == 0) {
      // ---- GN stats partials (tasks 0..511) + L3 weight prefetch (512..575)
      for (int task = blockIdx.x; task < 576; task += nb) {
        __syncthreads();
        if (task < 512) {
          const float4* p = (const float4*)(a.x_e + (size_t)task * 6912);
          float s = 0.f, ss = 0.f;
          for (int i = t; i < 1728; i += 256) {
            float4 v = p[i];
            s  += v.x + v.y + v.z + v.w;
            ss += v.x*v.x + v.y*v.y + v.z*v.z + v.w*v.w;
          }
          #pragma unroll
          for (int off = 32; off; off >>= 1) {
            s  += __shfl_down(s, off);
            ss += __shfl_down(ss, off);
          }
          if ((t & 63) == 0) { smem[(t >> 6) * 2] = s; smem[(t >> 6) * 2 + 1] = ss; }
          __syncthreads();
          if (t == 0) {
            float2 r;
            r.x = smem[0] + smem[2] + smem[4] + smem[6];
            r.y = smem[1] + smem[3] + smem[5] + smem[7];
            ((float2*)(a.ws + WS_STATSPART))[task] = r;
          }
        } else {
          float s = 0.f;
          int tid = (task - 512) * 256 + t;               // 0..16383
          const float4* g4 = (const float4*)a.gap_w;      // 221184 f4
          for (int i = tid; i < 221184; i += 16384) { float4 v = g4[i]; s += v.x + v.w; }
          const float4* a4 = (const float4*)a.w_cf;       // 65536 f4
          for (int i = tid; i < 65536;  i += 16384) { float4 v = a4[i]; s += v.x + v.w; }
          const float4* c4 = (const float4*)a.w_c;        // 32768 f4
          for (int i = tid; i < 32768;  i += 16384) { float4 v = c4[i]; s += v.x + v.w; }
          if (tid < 1024) { float4 v = ((const float4*)a.w_a1)[tid]; s += v.x; }
          if (tid < 192)  { float4 v = ((const float4*)a.emb)[tid];  s += v.x; }
          if (tid < 128)  { float4 v = ((const float4*)a.b_cf)[tid]; s += v.x; }
          if (s == 1.2345e30f) a.ws[WS_SINK] = s;         // never taken; keeps loads live
        }
      }
    } else if (ph == 1) {
      // ---- GN+ReLU window partial sums, z-quarters (1024 tasks) ----------
      for (int task = blockIdx.x; task < 1024; task += nb) {
        __syncthreads();
        int zq = task & 3;
        int bc = task >> 2;
        int b = bc >> 7, c = bc & 127;
        int bg = b * 16 + (c >> 3);
        const float2* sp = (const float2*)(a.ws + WS_STATSPART) + bg * 16;
        float S = 0.f, SS = 0.f;
        #pragma unroll
        for (int j = 0; j < 16; j++) { float2 r = sp[j]; S += r.x; SS += r.y; }
        float mu   = S * (1.f / 110592.f);
        float var  = SS * (1.f / 110592.f) - mu * mu;
        float rstd = rsqrtf(var + 1e-5f);
        float ga = a.gn_g[c] * rstd;
        float be = a.gn_b[c] - mu * ga;

        int nz     = (zq < 3) ? 3 : 2;
        int planes = 2 * nz + 1;       // 7 or 5
        int startf = zq * 3456;
        int nf4    = planes * 144;
        const float4* p = (const float4*)(a.x_e + (size_t)bc * NSPAT + startf);
        float4* l4 = (float4*)smem;
        for (int i = t; i < nf4; i += 256) {
          float4 v = p[i];
          float4 r;
          r.x = fmaxf(v.x * ga + be, 0.f);
          r.y = fmaxf(v.y * ga + be, 0.f);
          r.z = fmaxf(v.z * ga + be, 0.f);
          r.w = fmaxf(v.w * ga + be, 0.f);
          l4[i] = r;
        }
        __syncthreads();

        float acc[27];
        #pragma unroll
        for (int k = 0; k < 27; k++) acc[k] = 0.f;
        int npos = nz * 121;
        for (int pidx = t; pidx < npos; pidx += 256) {
          int zl = pidx / 121, rem = pidx % 121;
          int y = rem / 11, xx = rem % 11;
          int base = zl * 1152 + y * 48 + xx * 2;
          #pragma unroll
          for (int kz = 0; kz < 3; kz++)
            #pragma unroll
            for (int ky = 0; ky < 3; ky++)
              #pragma unroll
              for (int kx = 0; kx < 3; kx++)
                acc[kz * 9 + ky * 3 + kx] += smem[base + kz * 576 + ky * 24 + kx];
        }
        #pragma unroll
        for (int k = 0; k < 27; k++)
          for (int off = 32; off; off >>= 1)
            acc[k] += __shfl_down(acc[k], off);
        float* part = smem + 4032;
        __syncthreads();
        int wid = t >> 6, lane = t & 63;
        if (lane == 0)
          #pragma unroll
          for (int k = 0; k < 27; k++) part[wid * 27 + k] = acc[k];
        __syncthreads();
        if (t < 27) {
          float v = part[t] + part[27 + t] + part[54 + t] + part[81 + t];
          a.ws[WS_WINS + task * 27 + t] = v;   // [bc][zq][tap]
        }
      }
    } else if (ph == 2) {
      // ---- x_feat = wins . gap_w /1331 + gap_b (128 tasks) ---------------
      for (int task = blockIdx.x; task < 128; task += nb) {
        __syncthreads();
        int b = task >> 6;
        int oc = task & 63;
        const float* wp = a.ws + WS_WINS + b * 13824;   // [c][4][27]
        for (int i = t; i < 3456; i += 256) {
          int c = i / 27, k = i - c * 27;
          const float* q = wp + c * 108 + k;
          smem[i] = q[0] + q[27] + q[54] + q[81];
        }
        __syncthreads();
        int olocal = t >> 6;
        int lane = t & 63;
        int o = oc * 4 + olocal;
        const float4* w4 = (const float4*)(a.gap_w + (size_t)o * 3456);
        const float4* s4 = (const float4*)smem;
        float acc = 0.f;
        for (int i = lane; i < 864; i += 64) {
          float4 wv = w4[i], sv = s4[i];
          acc += wv.x * sv.x + wv.y * sv.y + wv.z * sv.z + wv.w * sv.w;
        }
        #pragma unroll
        for (int off = 32; off; off >>= 1) acc += __shfl_down(acc, off);
        if (lane == 0)
          a.ws[WS_XF + b * 256 + o] = acc * (1.f / 1331.f) + a.gap_b[o];
      }
    } else if (ph == 3) {
      // ---- p = relu(W_cf . [xf, emb] + b_cf) (24 tasks) ------------------
      for (int task = blockIdx.x; task < 24; task += nb) {
        __syncthreads();
        int bk = task >> 2;
        int q = task & 3;
        int b = bk / 3, k = bk % 3;
        float* cond = smem;            // 512
        float* ph2  = smem + 512;      // 256
        for (int i = t; i < 512; i += 256)
          cond[i] = (i < 256) ? a.ws[WS_XF + b * 256 + i] : a.emb[k * 256 + (i - 256)];
        __syncthreads();
        int ol = t & 127, half = t >> 7;
        int o = q * 128 + ol;
        const float4* w4 = (const float4*)(a.w_cf + (size_t)o * 512) + half * 64;
        const float4* c4 = (const float4*)cond + half * 64;
        float acc = 0.f;
        #pragma unroll 8
        for (int j = 0; j < 64; j++) {
          float4 wv = w4[j], cv = c4[j];
          acc += wv.x * cv.x + wv.y * cv.y + wv.z * cv.z + wv.w * cv.w;
        }
        ph2[half * 128 + ol] = acc;
        __syncthreads();
        if (t < 128)
          a.ws[WS_P + bk * 512 + o] = fmaxf(ph2[t] + ph2[128 + t] + a.b_cf[o], 0.f);
      }
    } else if (ph == 4) {
      // ---- c = W_c.p + b_c; attention MLP; effw (6 tasks) ----------------
      for (int task = blockIdx.x; task < 6; task += nb) {
        __syncthreads();
        int k = task % 3;
        float* pbuf = smem;            // 512
        float* cbuf = smem + 512;      // 256
        float* hid  = smem + 768;      // 16
        for (int i = t; i < 512; i += 256) pbuf[i] = a.ws[WS_P + task * 512 + i];
        __syncthreads();
        {
          const float4* w4 = (const float4*)(a.w_c + (size_t)t * 512);
          const float4* p4 = (const float4*)pbuf;
          float acc = 0.f;
          #pragma unroll 8
          for (int j = 0; j < 128; j++) {
            float4 wv = w4[j], pv = p4[j];
            acc += wv.x * pv.x + wv.y * pv.y + wv.z * pv.z + wv.w * pv.w;
          }
          cbuf[t] = acc + a.b_c[t];
        }
        __syncthreads();
        if (t < 16) {
          const float4* w4 = (const float4*)(a.w_a1 + t * 256);
          const float4* c4 = (const float4*)cbuf;
          float acc = a.b_a1[t];
          for (int j = 0; j < 64; j++) {
            float4 wv = w4[j], cv = c4[j];
            acc += wv.x * cv.x + wv.y * cv.y + wv.z * cv.z + wv.w * cv.w;
          }
          hid[t] = fmaxf(acc, 0.f);
        }
        __syncthreads();
        if (t < 32) {
          float acc = a.b_a2[t];
          #pragma unroll
          for (int j = 0; j < 16; j++) acc += a.w_a2[t * 16 + j] * hid[j];
          float gate = 1.f / (1.f + __expf(-acc));
          a.ws[WS_EFFW + task * 32 + t] = gate * a.w_seg[k * 32 + t];
        }
      }
    } else {
      // ---- seg: out[b,k,p] = sum_c effw*pred + b_seg ---------------------
      __syncthreads();
      if (t < 192) smem[t] = a.ws[WS_EFFW + t];
      __syncthreads();
      float s0 = a.b_seg[0], s1 = a.b_seg[1], s2 = a.b_seg[2];
      int stride = nb * 256;
      for (int gid = blockIdx.x * 256 + t; gid < 442368; gid += stride) {
        int b = gid / P4;
        int p = gid - b * P4;
        const float4* pr = (const float4*)a.pred + (size_t)b * 32 * P4 + p;
        const float* e = smem + b * 96;
        float4 a0 = {0, 0, 0, 0}, a1 = a0, a2 = a0;
        #pragma unroll 8
        for (int c = 0; c < 32; c++) {
          float4 v = pr[(size_t)c * P4];
          float w0 = e[c], w1 = e[32 + c], w2 = e[64 + c];
          a0.x += w0 * v.x; a0.y += w0 * v.y; a0.z += w0 * v.z; a0.w += w0 * v.w;
          a1.x += w1 * v.x; a1.y += w1 * v.y; a1.z += w1 * v.z; a1.w += w1 * v.w;
          a2.x += w2 * v.x; a2.y += w2 * v.y; a2.z += w2 * v.z; a2.w += w2 * v.w;
        }
        a0.x += s0; a0.y += s0; a0.z += s0; a0.w += s0;
        a1.x += s1; a1.y += s1; a1.z += s1; a1.w += s1;
        a2.x += s2; a2.y += s2; a2.z += s2; a2.w += s2;
        float4* o4 = (float4*)a.out + (size_t)b * 3 * P4 + p;
        o4[0]      = a0;
        o4[P4]     = a1;
        o4[2 * P4] = a2;
      }
    }
    if (ph < ph_hi) cg::this_grid().sync();
  }
}

extern "C" void kernel_launch(void* const* d_in, const int* in_sizes, int n_in,
                              void* d_out, int out_size, void* d_ws, size_t ws_size,
                              hipStream_t stream) {
  KArgs a;
  a.x_e   = (const float*)d_in[0];
  a.pred  = (const float*)d_in[1];
  a.gn_g  = (const float*)d_in[2];
  a.gn_b  = (const float*)d_in[3];
  a.gap_w = (const float*)d_in[4];
  a.gap_b = (const float*)d_in[5];
  a.w_cf  = (const float*)d_in[6];
  a.b_cf  = (const float*)d_in[7];
  a.w_c   = (const float*)d_in[8];
  a.b_c   = (const float*)d_in[9];
  a.w_a1  = (const float*)d_in[10];
  a.b_a1  = (const float*)d_in[11];
  a.w_a2  = (const float*)d_in[12];
  a.b_a2  = (const float*)d_in[13];
  a.emb   = (const float*)d_in[14];
  a.w_seg = (const float*)d_in[15];
  a.b_seg = (const float*)d_in[16];
  a.ws    = (float*)d_ws;
  a.out   = (float*)d_out;

  // Size the cooperative grid from the runtime's own occupancy number.
  int maxb = 0;
  hipError_t qerr = hipOccupancyMaxActiveBlocksPerMultiprocessor(
      &maxb, (const void*)fused_kernel, 256, 0);

  bool coop_ok = false;
  if (qerr == hipSuccess && maxb > 0) {
    int grid = maxb * 256;             // 256 CUs on MI355X
    if (grid > 1024) grid = 1024;
    int ph_lo = 0, ph_hi = 5;
    void* args[] = {&a, &ph_lo, &ph_hi};
    hipError_t lerr = hipLaunchCooperativeKernel(
        (const void*)fused_kernel, dim3(grid), dim3(256), args, 0, stream);
    coop_ok = (lerr == hipSuccess);
  }

  if (!coop_ok) {
    // Fallback: one phase per launch; launch boundary = global sync.
    fused_kernel<<<576,  256, 0, stream>>>(a, 0, 0);
    fused_kernel<<<1024, 256, 0, stream>>>(a, 1, 1);
    fused_kernel<<<128,  256, 0, stream>>>(a, 2, 2);
    fused_kernel<<<24,   256, 0, stream>>>(a, 3, 3);
    fused_kernel<<<6,    256, 0, stream>>>(a, 4, 4);
    fused_kernel<<<1728, 256, 0, stream>>>(a, 5, 5);
  }
}

// Round 5
// 114.750 us; speedup vs baseline: 3.2534x; 3.2534x over previous
//
#include <hip/hip_runtime.h>
#include <hip/hip_bf16.h>

// ---------------------------------------------------------------------------
//   x_e  [2,128,24,24,24]   pred [2,32,96,96,96]   out [2,3,96,96,96] fp32
//   conv(128->256,k3,s2,VALID) -> 11^3 positions; mean∘conv commutes, so
//   conv+pool collapses to 27 window-sums per channel (exact).
//   Pipeline: K1 stats+prefetch -> K2 winsum -> K3 xfeat+controller (spin
//   barriers among 128 resident blocks) -> K4 seg (the big streaming op).
// ---------------------------------------------------------------------------

#define NSPAT 13824      // 24^3
#define P4    221184     // 96^3/4

// ws layout (floats)
#define WS_STATSPART 0       // 512 float2 -> 1024
#define WS_WINS      1024    // [2][128][4][27] = 27648
#define WS_XF        28672   // 512
#define WS_P         29184   // 6*512 = 3072
#define WS_C         32256   // 6*256 = 1536
#define WS_EFFW      33792   // 192
#define WS_BAR       33984   // 2 ints (count, generation)
#define WS_SINK      33992

// Generation-based spin barrier among nb co-resident blocks.
// bar[0]=count (must start 0; self-resets), bar[1]=generation (any value).
__device__ __forceinline__ void spin_barrier(int* bar, int nb) {
  __syncthreads();
  if (threadIdx.x == 0) {
    __threadfence();                       // release prior writes
    int gen = atomicAdd(&bar[1], 0);       // read current generation
    int old = atomicAdd(&bar[0], 1);       // arrive
    if (old == nb - 1) {
      atomicExch(&bar[0], 0);              // reset for next use
      __threadfence();
      atomicAdd(&bar[1], 1);               // release
    } else {
      while (atomicAdd(&bar[1], 0) == gen) __builtin_amdgcn_s_sleep(8);
    }
    __threadfence();                       // acquire
  }
  __syncthreads();
}

// ---------------------------------------------------------------------------
// K1: GN stats partials (blocks 0..511) + L3 weight prefetch (512..575).
// Also zeroes K3's barrier counter.
// ---------------------------------------------------------------------------
__global__ __launch_bounds__(256) void k1_stats_kernel(
    const float* __restrict__ x, const float* __restrict__ gap_w,
    const float* __restrict__ w_cf, const float* __restrict__ w_c,
    const float* __restrict__ w_a1, const float* __restrict__ emb,
    float* __restrict__ ws) {
  if (blockIdx.x == 0 && threadIdx.x == 0)
    atomicExch(&((int*)(ws + WS_BAR))[0], 0);
  if (blockIdx.x >= 512) {
    float s = 0.f;
    int tid = (blockIdx.x - 512) * 256 + threadIdx.x;   // 0..16383
    const float4* g4 = (const float4*)gap_w;            // 221184 f4
    for (int i = tid; i < 221184; i += 16384) { float4 v = g4[i]; s += v.x + v.w; }
    const float4* a4 = (const float4*)w_cf;             // 65536 f4
    for (int i = tid; i < 65536;  i += 16384) { float4 v = a4[i]; s += v.x + v.w; }
    const float4* c4 = (const float4*)w_c;              // 32768 f4
    for (int i = tid; i < 32768;  i += 16384) { float4 v = c4[i]; s += v.x + v.w; }
    if (tid < 1024) { float4 v = ((const float4*)w_a1)[tid]; s += v.x; }
    if (tid < 192)  { float4 v = ((const float4*)emb)[tid];  s += v.x; }
    if (s == 1.2345e30f) ws[WS_SINK] = s;   // never taken; keeps loads live
    return;
  }
  int blk = blockIdx.x;                     // bg*16 + chunk
  const float4* p = (const float4*)(x + (size_t)blk * 6912);
  float s = 0.f, ss = 0.f;
  for (int i = threadIdx.x; i < 1728; i += 256) {
    float4 v = p[i];
    s  += v.x + v.y + v.z + v.w;
    ss += v.x*v.x + v.y*v.y + v.z*v.z + v.w*v.w;
  }
  #pragma unroll
  for (int off = 32; off; off >>= 1) {
    s  += __shfl_down(s, off);
    ss += __shfl_down(ss, off);
  }
  __shared__ float a[4], b2[4];
  int wid = threadIdx.x >> 6, lane = threadIdx.x & 63;
  if (lane == 0) { a[wid] = s; b2[wid] = ss; }
  __syncthreads();
  if (threadIdx.x == 0) {
    float2 r;
    r.x = a[0] + a[1] + a[2] + a[3];
    r.y = b2[0] + b2[1] + b2[2] + b2[3];
    ((float2*)(ws + WS_STATSPART))[blk] = r;
  }
}

// ---------------------------------------------------------------------------
// K2: per-(b,c,zquarter) GN+ReLU in LDS, 27 window partial sums. 1024 blocks.
// ---------------------------------------------------------------------------
__global__ __launch_bounds__(256) void k2_winsum_kernel(
    const float* __restrict__ x, const float* __restrict__ gn_g,
    const float* __restrict__ gn_b, float* __restrict__ ws) {
  int task = blockIdx.x;
  int zq = task & 3;
  int bc = task >> 2;
  int b = bc >> 7, c = bc & 127;
  int bg = b * 16 + (c >> 3);
  const float2* sp = (const float2*)(ws + WS_STATSPART) + bg * 16;
  float S = 0.f, SS = 0.f;
  #pragma unroll
  for (int j = 0; j < 16; j++) { float2 r = sp[j]; S += r.x; SS += r.y; }
  float mu   = S * (1.f / 110592.f);
  float var  = SS * (1.f / 110592.f) - mu * mu;
  float rstd = rsqrtf(var + 1e-5f);
  float ga = gn_g[c] * rstd;
  float be = gn_b[c] - mu * ga;

  __shared__ float smem[4140];
  int t = threadIdx.x;
  int nz     = (zq < 3) ? 3 : 2;
  int planes = 2 * nz + 1;             // 7 or 5
  int startf = zq * 3456;
  int nf4    = planes * 144;
  const float4* p = (const float4*)(x + (size_t)bc * NSPAT + startf);
  float4* l4 = (float4*)smem;
  for (int i = t; i < nf4; i += 256) {
    float4 v = p[i];
    float4 r;
    r.x = fmaxf(v.x * ga + be, 0.f);
    r.y = fmaxf(v.y * ga + be, 0.f);
    r.z = fmaxf(v.z * ga + be, 0.f);
    r.w = fmaxf(v.w * ga + be, 0.f);
    l4[i] = r;
  }
  __syncthreads();

  float acc[27];
  #pragma unroll
  for (int k = 0; k < 27; k++) acc[k] = 0.f;
  int npos = nz * 121;
  for (int pidx = t; pidx < npos; pidx += 256) {
    int zl = pidx / 121, rem = pidx % 121;
    int y = rem / 11, xx = rem % 11;
    int base = zl * 1152 + y * 48 + xx * 2;
    #pragma unroll
    for (int kz = 0; kz < 3; kz++)
      #pragma unroll
      for (int ky = 0; ky < 3; ky++)
        #pragma unroll
        for (int kx = 0; kx < 3; kx++)
          acc[kz * 9 + ky * 3 + kx] += smem[base + kz * 576 + ky * 24 + kx];
  }
  #pragma unroll
  for (int k = 0; k < 27; k++)
    for (int off = 32; off; off >>= 1)
      acc[k] += __shfl_down(acc[k], off);
  float* part = smem + 4032;
  __syncthreads();
  int wid = t >> 6, lane = t & 63;
  if (lane == 0)
    #pragma unroll
    for (int k = 0; k < 27; k++) part[wid * 27 + k] = acc[k];
  __syncthreads();
  if (t < 27) {
    float v = part[t] + part[27 + t] + part[54 + t] + part[81 + t];
    ws[WS_WINS + task * 27 + t] = v;
  }
}

// ---------------------------------------------------------------------------
// K3: xfeat -> bar -> ctrl1 -> bar -> ctrl2 -> bar -> ctrl3.  128 blocks
// (<= 256 CUs so all co-resident; spin barrier is safe).
// ---------------------------------------------------------------------------
__global__ __launch_bounds__(256) void k3_chain_kernel(
    const float* __restrict__ gap_w, const float* __restrict__ gap_b,
    const float* __restrict__ w_cf,  const float* __restrict__ b_cf,
    const float* __restrict__ w_c,   const float* __restrict__ b_c,
    const float* __restrict__ w_a1,  const float* __restrict__ b_a1,
    const float* __restrict__ w_a2,  const float* __restrict__ b_a2,
    const float* __restrict__ emb,   const float* __restrict__ w_seg,
    float* ws) {
  __shared__ float smem[3456];
  int* bar = (int*)(ws + WS_BAR);
  const int t   = threadIdx.x;
  const int blk = blockIdx.x;

  // ---- B1: x_feat[b,o] = dot(wins[b], gap_w[o])/1331 + gap_b[o] ----------
  {
    int b = blk >> 6;
    int oc = blk & 63;                 // 64 chunks of 4 outputs
    const float* wp = ws + WS_WINS + b * 13824;   // [c][4][27]
    for (int i = t; i < 3456; i += 256) {
      int c = i / 27, k = i - c * 27;
      const float* q = wp + c * 108 + k;
      smem[i] = q[0] + q[27] + q[54] + q[81];
    }
    __syncthreads();
    int olocal = t >> 6;
    int lane = t & 63;
    int o = oc * 4 + olocal;
    const float4* w4 = (const float4*)(gap_w + (size_t)o * 3456);
    const float4* s4 = (const float4*)smem;
    float acc = 0.f;
    for (int i = lane; i < 864; i += 64) {
      float4 wv = w4[i], sv = s4[i];
      acc += wv.x * sv.x + wv.y * sv.y + wv.z * sv.z + wv.w * sv.w;
    }
    #pragma unroll
    for (int off = 32; off; off >>= 1) acc += __shfl_down(acc, off);
    if (lane == 0) ws[WS_XF + b * 256 + o] = acc * (1.f / 1331.f) + gap_b[o];
  }
  spin_barrier(bar, 128);

  // ---- B2: p[bk,o] = relu(W_cf[o] . [xf[b];emb[k]] + b_cf[o]) ------------
  // block handles 4 rows o = blk*4..+3, all 6 bk.
  {
    for (int i = t; i < 1280; i += 256)
      smem[i] = (i < 512) ? ws[WS_XF + i] : emb[i - 512];
    __syncthreads();
    int r = t >> 6, lane = t & 63;
    int o = blk * 4 + r;
    const float4* w4  = (const float4*)(w_cf + (size_t)o * 512);
    const float4* xf4 = (const float4*)smem;          // [2][64]
    const float4* em4 = (const float4*)(smem + 512);  // [3][64]
    float4 wlo = w4[lane], whi = w4[lane + 64];
    float acc[6];
    #pragma unroll
    for (int bk = 0; bk < 6; bk++) {
      int b = (bk >= 3), k = bk - b * 3;
      float4 xv = xf4[b * 64 + lane];
      float4 ev = em4[k * 64 + lane];
      acc[bk] = wlo.x*xv.x + wlo.y*xv.y + wlo.z*xv.z + wlo.w*xv.w
              + whi.x*ev.x + whi.y*ev.y + whi.z*ev.z + whi.w*ev.w;
    }
    #pragma unroll
    for (int bk = 0; bk < 6; bk++)
      #pragma unroll
      for (int off = 32; off; off >>= 1)
        acc[bk] += __shfl_down(acc[bk], off);
    if (lane == 0) {
      float bb = b_cf[o];
      #pragma unroll
      for (int bk = 0; bk < 6; bk++)
        ws[WS_P + bk * 512 + o] = fmaxf(acc[bk] + bb, 0.f);
    }
  }
  spin_barrier(bar, 128);

  // ---- B3: c[bk,o] = W_c[o] . p[bk] + b_c[o] ------------------------------
  // block handles 2 rows o = blk*2..+1, all 6 bk. threads 0..127 active.
  {
    for (int i = t; i < 3072; i += 256) smem[i] = ws[WS_P + i];
    __syncthreads();
    if (t < 128) {
      int r = t >> 6, lane = t & 63;
      int o = blk * 2 + r;
      const float4* w4 = (const float4*)(w_c + (size_t)o * 512);
      const float4* p4 = (const float4*)smem;         // [6][128]
      float4 wlo = w4[lane], whi = w4[lane + 64];
      float acc[6];
      #pragma unroll
      for (int bk = 0; bk < 6; bk++) {
        float4 plo = p4[bk * 128 + lane];
        float4 phi = p4[bk * 128 + lane + 64];
        acc[bk] = wlo.x*plo.x + wlo.y*plo.y + wlo.z*plo.z + wlo.w*plo.w
                + whi.x*phi.x + whi.y*phi.y + whi.z*phi.z + whi.w*phi.w;
      }
      #pragma unroll
      for (int bk = 0; bk < 6; bk++)
        #pragma unroll
        for (int off = 32; off; off >>= 1)
          acc[bk] += __shfl_down(acc[bk], off);
      if (lane == 0) {
        float bb = b_c[o];
        #pragma unroll
        for (int bk = 0; bk < 6; bk++)
          ws[WS_C + bk * 256 + o] = acc[bk] + bb;
      }
    }
  }
  spin_barrier(bar, 128);

  // ---- B4: attention MLP + effw (block 0 only) ----------------------------
  if (blk == 0) {
    for (int i = t; i < 1536; i += 256) smem[i] = ws[WS_C + i];
    __syncthreads();
    __shared__ float hid[96];
    if (t < 96) {
      int bk = t >> 4, h = t & 15;
      const float4* w4 = (const float4*)(w_a1 + h * 256);
      const float4* c4 = (const float4*)(smem + bk * 256);
      float acc = b_a1[h];
      for (int j = 0; j < 64; j++) {
        float4 wv = w4[j], cv = c4[j];
        acc += wv.x*cv.x + wv.y*cv.y + wv.z*cv.z + wv.w*cv.w;
      }
      hid[bk * 16 + h] = fmaxf(acc, 0.f);
    }
    __syncthreads();
    if (t < 192) {
      int bk = t >> 5, o = t & 31;
      int k = bk - (bk >= 3) * 3;
      float acc = b_a2[o];
      #pragma unroll
      for (int j = 0; j < 16; j++) acc += w_a2[o * 16 + j] * hid[bk * 16 + j];
      float gate = 1.f / (1.f + __expf(-acc));
      ws[WS_EFFW + bk * 32 + o] = gate * w_seg[k * 32 + o];
    }
  }
}

// ---------------------------------------------------------------------------
// K4: out[b,k,p] = sum_c effw[b,k,c]*pred[b,c,p] + b_seg[k].  1728 blocks.
// ---------------------------------------------------------------------------
__global__ __launch_bounds__(256) void k4_seg_kernel(
    const float* __restrict__ pred, const float* __restrict__ ws_in,
    const float* __restrict__ b_seg, float* __restrict__ out) {
  __shared__ float ew[192];
  if (threadIdx.x < 192) ew[threadIdx.x] = ws_in[WS_EFFW + threadIdx.x];
  __syncthreads();
  int gid = blockIdx.x * 256 + threadIdx.x;     // < 442368 exactly
  int b = gid / P4;
  int p = gid - b * P4;
  const float4* pr = (const float4*)pred + (size_t)b * 32 * P4 + p;
  const float* e = ew + b * 96;
  float4 a0 = {0, 0, 0, 0}, a1 = a0, a2 = a0;
  #pragma unroll 8
  for (int c = 0; c < 32; c++) {
    float4 v = pr[(size_t)c * P4];
    float w0 = e[c], w1 = e[32 + c], w2 = e[64 + c];
    a0.x += w0 * v.x; a0.y += w0 * v.y; a0.z += w0 * v.z; a0.w += w0 * v.w;
    a1.x += w1 * v.x; a1.y += w1 * v.y; a1.z += w1 * v.z; a1.w += w1 * v.w;
    a2.x += w2 * v.x; a2.y += w2 * v.y; a2.z += w2 * v.z; a2.w += w2 * v.w;
  }
  float s0 = b_seg[0], s1 = b_seg[1], s2 = b_seg[2];
  a0.x += s0; a0.y += s0; a0.z += s0; a0.w += s0;
  a1.x += s1; a1.y += s1; a1.z += s1; a1.w += s1;
  a2.x += s2; a2.y += s2; a2.z += s2; a2.w += s2;
  float4* o4 = (float4*)out + (size_t)b * 3 * P4 + p;
  o4[0]      = a0;
  o4[P4]     = a1;
  o4[2 * P4] = a2;
}

extern "C" void kernel_launch(void* const* d_in, const int* in_sizes, int n_in,
                              void* d_out, int out_size, void* d_ws, size_t ws_size,
                              hipStream_t stream) {
  const float* x_e   = (const float*)d_in[0];
  const float* pred  = (const float*)d_in[1];
  const float* gn_g  = (const float*)d_in[2];
  const float* gn_b  = (const float*)d_in[3];
  const float* gap_w = (const float*)d_in[4];
  const float* gap_b = (const float*)d_in[5];
  const float* w_cf  = (const float*)d_in[6];
  const float* b_cf  = (const float*)d_in[7];
  const float* w_c   = (const float*)d_in[8];
  const float* b_c   = (const float*)d_in[9];
  const float* w_a1  = (const float*)d_in[10];
  const float* b_a1  = (const float*)d_in[11];
  const float* w_a2  = (const float*)d_in[12];
  const float* b_a2  = (const float*)d_in[13];
  const float* emb   = (const float*)d_in[14];
  const float* w_seg = (const float*)d_in[15];
  const float* b_seg = (const float*)d_in[16];
  float* ws  = (float*)d_ws;
  float* out = (float*)d_out;

  k1_stats_kernel<<<576, 256, 0, stream>>>(x_e, gap_w, w_cf, w_c, w_a1, emb, ws);
  k2_winsum_kernel<<<1024, 256, 0, stream>>>(x_e, gn_g, gn_b, ws);
  k3_chain_kernel<<<128, 256, 0, stream>>>(gap_w, gap_b, w_cf, b_cf, w_c, b_c,
                                           w_a1, b_a1, w_a2, b_a2, emb, w_seg, ws);
  k4_seg_kernel<<<1728, 256, 0, stream>>>(pred, ws, b_seg, out);
}